// Round 2
// 278.366 us; speedup vs baseline: 1.1280x; 1.1280x over previous
//
#include <hip/hip_runtime.h>
#include <hip/hip_bf16.h>

#define BATCH 4
#define SEQ   2048
#define DM    1024
#define NH    16
#define DK    64
#define BH    (BATCH*NH)   // 64

typedef __attribute__((ext_vector_type(8))) short  bv8;   // 8 bf16 (4 VGPRs) MFMA frag
typedef __attribute__((ext_vector_type(4))) short  sv4;   // 4 bf16 (8B)
typedef __attribute__((ext_vector_type(4))) float  f32x4;

__device__ __forceinline__ short f2b(float f) {
    unsigned u = __builtin_bit_cast(unsigned, f);
    u += 0x7fffu + ((u >> 16) & 1u);          // RNE
    return (short)(u >> 16);
}
__device__ __forceinline__ unsigned pk2(float lo, float hi) {  // bf16x2 pack
    unsigned ul = __builtin_bit_cast(unsigned, lo);
    unsigned uh = __builtin_bit_cast(unsigned, hi);
    ul += 0x7fffu + ((ul >> 16) & 1u);
    uh += 0x7fffu + ((uh >> 16) & 1u);
    return (ul >> 16) | (uh & 0xffff0000u);
}
__device__ __forceinline__ float b2f(short s) {
    unsigned u = ((unsigned)(unsigned short)s) << 16;
    return __builtin_bit_cast(float, u);
}

// async global->LDS, 16B per lane; LDS dest = wave-uniform base + lane*16;
// global source is PER-LANE — lanes must cover whole cache lines.
__device__ __forceinline__ void load_lds16(const short* g, short* l) {
    __builtin_amdgcn_global_load_lds(
        (const __attribute__((address_space(1))) void*)g,
        (__attribute__((address_space(3))) void*)l, 16, 0, 0);
}

// ---------------------------------------------------------------------------
// fp32 -> bf16 pre-convert. z=0: x (4096 blocks); z=1..4: Wq,Wk,Wv,Wo (512).
// ---------------------------------------------------------------------------
__global__ __launch_bounds__(256) void cvt_kernel(
    const float* __restrict__ x,
    const float* __restrict__ wq, const float* __restrict__ wk,
    const float* __restrict__ wv, const float* __restrict__ wo,
    short* __restrict__ Xb, short* __restrict__ Wb)
{
    const int z = blockIdx.y;
    const float* src; short* dst; int nblk;
    if (z == 0) { src = x; dst = Xb; nblk = 4096; }
    else {
        src = (z == 1) ? wq : (z == 2) ? wk : (z == 3) ? wv : wo;
        dst = Wb + (size_t)(z - 1) * (DM * DM);
        nblk = 512;
    }
    if ((int)blockIdx.x >= nblk) return;
    int idx = blockIdx.x * 256 + threadIdx.x;      // 8-elem chunk
    const float4* s4 = (const float4*)src + (size_t)idx * 2;
    float4 a = s4[0], b = s4[1];
    bv8 o;
    o[0] = f2b(a.x); o[1] = f2b(a.y); o[2] = f2b(a.z); o[3] = f2b(a.w);
    o[4] = f2b(b.x); o[5] = f2b(b.y); o[6] = f2b(b.z); o[7] = f2b(b.w);
    *(bv8*)(dst + (size_t)idx * 8) = o;
}

// ---------------------------------------------------------------------------
// GEMM (NT, all-bf16): unchanged (coalesced swizzled staging).
// ---------------------------------------------------------------------------
template<bool FINAL>
__global__ __launch_bounds__(256) void gemm_nt(
    const short* __restrict__ A, const short* __restrict__ Wall,
    short* __restrict__ Oq, short* __restrict__ Ok, short* __restrict__ Ov,
    float* __restrict__ FO)
{
    constexpr int K = 1024;
    __shared__ __align__(16) short As[128 * 64];   // 16 KB, slot16(r,c8)=r*8+(c8^(r&7))
    __shared__ __align__(16) short Ws[128 * 64];

    const int bn = blockIdx.x, bm = blockIdx.y, bz = blockIdx.z;
    const short* __restrict__ W = Wall + (size_t)bz * (DM * DM);
    const int tid = threadIdx.x;
    const int wave = tid >> 6, lane = tid & 63, lm = lane & 15, lq = lane >> 4;
    const int wr = wave >> 1, wc = wave & 1;
    const int row0 = bm * 128, col0 = bn * 128;

    f32x4 acc[4][4];
    for (int i = 0; i < 4; i++)
        for (int j = 0; j < 4; j++)
            acc[i][j] = f32x4{0.f, 0.f, 0.f, 0.f};

    const int rI = lane >> 3;              // row within instruction (0..7)
    const int cS = (lane & 7) ^ rI;        // swizzled 16B chunk (0..7)
    const short* gA[4]; const short* gW[4];
    short* lA[4]; short* lW[4];
    for (int j = 0; j < 4; j++) {
        int rl = wave * 32 + j * 8;
        gA[j] = A + (size_t)(row0 + rl + rI) * K + cS * 8;
        gW[j] = W + (size_t)(col0 + rl + rI) * K + cS * 8;
        lA[j] = &As[rl * 64];
        lW[j] = &Ws[rl * 64];
    }

    for (int kk = 0; kk < K; kk += 64) {
        for (int j = 0; j < 4; j++) {
            load_lds16(gA[j], lA[j]);  gA[j] += 64;
            load_lds16(gW[j], lW[j]);  gW[j] += 64;
        }
        __syncthreads();

        for (int h = 0; h < 2; h++) {
            bv8 af[4], bf[4];
            for (int mt = 0; mt < 4; mt++) {
                int r = wr * 64 + mt * 16 + lm;
                af[mt] = *(const bv8*)&As[r * 64 + (((h * 4 + lq) ^ (lm & 7)) * 8)];
            }
            for (int nt = 0; nt < 4; nt++) {
                int r = wc * 64 + nt * 16 + lm;
                bf[nt] = *(const bv8*)&Ws[r * 64 + (((h * 4 + lq) ^ (lm & 7)) * 8)];
            }
            for (int mt = 0; mt < 4; mt++)
                for (int nt = 0; nt < 4; nt++)
                    acc[mt][nt] = __builtin_amdgcn_mfma_f32_16x16x32_bf16(af[mt], bf[nt], acc[mt][nt], 0, 0, 0);
        }
        __syncthreads();
    }

    for (int mt = 0; mt < 4; mt++) {
        int mbase = row0 + wr * 64 + mt * 16 + lq * 4;
        for (int nt = 0; nt < 4; nt++) {
            int n = col0 + wc * 64 + nt * 16 + lm;
            for (int r = 0; r < 4; r++) {
                float v = acc[mt][nt][r];
                int row = mbase + r;
                if constexpr (FINAL) {
                    FO[(size_t)row * DM + n] = v;
                } else {
                    int b = row >> 11, s = row & 2047;
                    int h = n >> 6, d = n & 63;
                    if (bz == 2)   // V^T: [BH][64][S]
                        Ov[((size_t)((b * NH + h) * DK + d)) * SEQ + s] = f2b(v);
                    else {
                        short* dst = (bz == 0) ? Oq : Ok;
                        dst[((size_t)((b * NH + h) * SEQ + s)) * DK + d] = f2b(v);
                    }
                }
            }
        }
    }
}

// ---------------------------------------------------------------------------
// RoPE in-place on [BH][S][64] bf16. grid.y: 0=Q (also applies 1/8 scale), 1=K.
// ---------------------------------------------------------------------------
__global__ __launch_bounds__(256) void rope_kernel(short* __restrict__ Qb, short* __restrict__ Kb)
{
    short* T = blockIdx.y ? Kb : Qb;
    const float scale = blockIdx.y ? 1.0f : 0.125f;
    int idx = blockIdx.x * 256 + threadIdx.x;     // 8-elem chunk
    int s  = (idx >> 3) & (SEQ - 1);
    int d0 = (idx & 7) * 8;
    bv8 v = *(const bv8*)(T + (size_t)idx * 8);
    bv8 o;
    for (int j = 0; j < 4; j++) {
        int i = (d0 >> 1) + j;                    // pair index 0..31
        float invrev = __builtin_amdgcn_exp2f((float)i * -0.41522499f) * 0.15915494309f;
        float rev = __builtin_amdgcn_fractf((float)s * invrev);
        float sn = __builtin_amdgcn_sinf(rev);
        float cs = __builtin_amdgcn_cosf(rev);
        float e  = b2f(v[2 * j]);
        float od = b2f(v[2 * j + 1]);
        o[2 * j]     = f2b((e * cs - od * sn) * scale);
        o[2 * j + 1] = f2b((e * sn + od * cs) * scale);
    }
    *(bv8*)(T + (size_t)idx * 8) = o;
}

// ---------------------------------------------------------------------------
// Flash attention v6. grid (S/256, BH), 256 thr = 4 waves; wave owns 32 q-rows.
//
// v6 change: per-CU LOAD BALANCE. v5 used grid (S/128, BH) = 1024 blocks with
// work per block proportional to (qt+1) — a 16x spread. Since all 1024 blocks
// are resident at once (4 blocks/CU), there is no scheduling freedom, and with
// round-robin placement CU i gets 4 blocks of the SAME qt = 15 - (i%16): the
// critical-path CUs ran ~128 tile-steps vs a balanced 68 (OccupancyPercent
// 17%, all pipes <40%). v6 gives every block the complementary q-tile pair
// (15-x, x), processed sequentially: exactly 34 tile-steps per block, balanced
// by construction, robust to any dispatch order. K/V stream bases are
// kt-relative and shared across both passes; LDS double-buffer resets at each
// pass prologue (the in-loop trailing __syncthreads fences buffer reuse).
//
// Inner structure unchanged from v5: K/V staged via async global_load_lds
// (double-buffered, XOR-swizzled); S^T = mfma(kf, qf) so each lane owns one
// query (lm) and 16 keys; mask/exp/l-sum are lane-local; PV uses the psi
// key-order lane-local repack (8 pk2s) + two contiguous 8B LDS reads per
// (nt,h) from the swizzled V^T tile. LDS = 32 KB.
// ---------------------------------------------------------------------------
__global__ __launch_bounds__(256, 4) void attn_kernel(
    const short* __restrict__ Qb, const short* __restrict__ Kb,
    const short* __restrict__ Vb, short* __restrict__ Cb)
{
    __shared__ __align__(16) short Ks[2][4096];   // [buf][key*64 + swz] 8KB/buf
    __shared__ __align__(16) short Vs[2][4096];   // [buf][d*64 + swz]

    const int bh = blockIdx.y;
    const int tid = threadIdx.x, wave = tid >> 6, lane = tid & 63;
    const int lm = lane & 15, lq = lane >> 4;
    const size_t base = (size_t)bh * SEQ * DK;

    const int sr = lane >> 3;
    const int sc = (lane & 7) ^ sr;
    const short* gK0 = Kb + base + (size_t)(wave * 16 + sr) * DK + sc * 8;
    const short* gK1 = Kb + base + (size_t)(wave * 16 + 8 + sr) * DK + sc * 8;
    const short* gV0 = Vb + base + (size_t)(wave * 16 + sr) * SEQ + sc * 8;
    const short* gV1 = Vb + base + (size_t)(wave * 16 + 8 + sr) * SEQ + sc * 8;
    short* lK0[2] = { &Ks[0][(wave * 16) * 64],     &Ks[1][(wave * 16) * 64] };
    short* lK1[2] = { &Ks[0][(wave * 16 + 8) * 64], &Ks[1][(wave * 16 + 8) * 64] };
    short* lV0[2] = { &Vs[0][(wave * 16) * 64],     &Vs[1][(wave * 16) * 64] };
    short* lV1[2] = { &Vs[0][(wave * 16 + 8) * 64], &Vs[1][(wave * 16 + 8) * 64] };

    const int sw = lm & 7;
    const int bb = bh >> 4, hh = bh & 15;
    constexpr int NQT = SEQ / 128;                 // 16 q-tiles

    for (int pass = 0; pass < 2; ++pass) {
        // complementary pair: pass 0 -> heavy qt = 15-x, pass 1 -> light qt = x
        const int qt = pass ? (int)blockIdx.x : (NQT - 1 - (int)blockIdx.x);
        const int q0 = qt * 128;

        // Q frags (used as MFMA B-operand; same lane layout as A)
        bv8 aQ[2][2];
        for (int mg = 0; mg < 2; mg++) {
            const short* qp = Qb + base + (size_t)(q0 + wave * 32 + mg * 16 + lm) * DK + lq * 8;
            aQ[mg][0] = *(const bv8*)qp;
            aQ[mg][1] = *(const bv8*)(qp + 32);
        }

        f32x4 oacc[2][4];
        float rsum[2] = {0.f, 0.f};               // per-lane: one query (lm) per mg
        for (int mg = 0; mg < 2; mg++)
            for (int nt = 0; nt < 4; nt++) oacc[mg][nt] = f32x4{0.f, 0.f, 0.f, 0.f};

        const int last = 2 * qt + 1;
        const int qrow_base = q0 + wave * 32 + lm;    // + mg*16 -> this lane's query

        load_lds16(gK0, lK0[0]);  load_lds16(gK1, lK1[0]);
        load_lds16(gV0, lV0[0]);  load_lds16(gV1, lV1[0]);
        __syncthreads();

        for (int kt = 0; kt <= last; ++kt) {
            const int b = kt & 1;
            if (kt < last) {                           // prefetch overlaps compute
                const size_t ko = (size_t)(kt + 1) * 64 * DK;
                const size_t vo = (size_t)(kt + 1) * 64;
                load_lds16(gK0 + ko, lK0[b ^ 1]);  load_lds16(gK1 + ko, lK1[b ^ 1]);
                load_lds16(gV0 + vo, lV0[b ^ 1]);  load_lds16(gV1 + vo, lV1[b ^ 1]);
            }

            // S^T tiles: t[mg][nt] reg r = S[query mg*16+lm][key kt*64+nt*16+lq*4+r]
            f32x4 t[2][4];
            for (int nt = 0; nt < 4; nt++) {
                const short* kp = &Ks[b][(nt * 16 + lm) * 64];
                bv8 kf0 = *(const bv8*)(kp + ((lq ^ sw) * 8));
                bv8 kf1 = *(const bv8*)(kp + (((4 + lq) ^ sw) * 8));
                for (int mg = 0; mg < 2; mg++) {
                    f32x4 z = f32x4{0.f, 0.f, 0.f, 0.f};
                    z = __builtin_amdgcn_mfma_f32_16x16x32_bf16(kf0, aQ[mg][0], z, 0, 0, 0);
                    z = __builtin_amdgcn_mfma_f32_16x16x32_bf16(kf1, aQ[mg][1], z, 0, 0, 0);
                    t[mg][nt] = z;
                }
            }

            // mask (diagonal region only) + exp + lane-local l-sum + lane-local
            // repack into PV A-frags (key order psi: j<4 -> tile 2h, j>=4 -> 2h+1)
            bv8 aP[2][2];
            for (int mg = 0; mg < 2; mg++) {
                const int qrow = qrow_base + mg * 16;
                if (kt >= 2 * qt) {
                    for (int nt = 0; nt < 4; nt++) {
                        int keyb = kt * 64 + nt * 16 + lq * 4;
                        for (int r = 0; r < 4; r++)
                            t[mg][nt][r] = (keyb + r <= qrow) ? t[mg][nt][r] : -1e30f;
                    }
                }
                for (int nt = 0; nt < 4; nt++)
                    for (int r = 0; r < 4; r++) {
                        float p = __builtin_amdgcn_exp2f(t[mg][nt][r] * 1.44269504f);
                        rsum[mg] += p;
                        t[mg][nt][r] = p;
                    }
                for (int h = 0; h < 2; h++) {
                    union { unsigned u[4]; bv8 v; } pk;
                    pk.u[0] = pk2(t[mg][2 * h][0],     t[mg][2 * h][1]);
                    pk.u[1] = pk2(t[mg][2 * h][2],     t[mg][2 * h][3]);
                    pk.u[2] = pk2(t[mg][2 * h + 1][0], t[mg][2 * h + 1][1]);
                    pk.u[3] = pk2(t[mg][2 * h + 1][2], t[mg][2 * h + 1][3]);
                    aP[mg][h] = pk.v;
                }
            }

            // O += P V with the psi key order: B-frag element j on lane (lq,lm) =
            // V[32h + (j>>2)*16 + lq*4 + (j&3)][d = nt*16+lm] -> two 8B reads.
            for (int nt = 0; nt < 4; nt++) {
                const short* vrow = &Vs[b][(nt * 16 + lm) * 64];
                for (int h = 0; h < 2; h++) {
                    int c8 = h * 4 + (lq >> 1);
                    union { sv4 q[2]; bv8 v; } vv;
                    vv.q[0] = *(const sv4*)(vrow + ((c8 ^ sw) * 8)       + (lq & 1) * 4);
                    vv.q[1] = *(const sv4*)(vrow + (((c8 ^ 2) ^ sw) * 8) + (lq & 1) * 4);
                    for (int mg = 0; mg < 2; mg++)
                        oacc[mg][nt] = __builtin_amdgcn_mfma_f32_16x16x32_bf16(aP[mg][h], vv.v, oacc[mg][nt], 0, 0, 0);
                }
            }
            __syncthreads();   // releases buf b for the next prefetch
        }

        // l-sum: add the 4 lq quadrants (each lane then has full sum for query lm)
        for (int mg = 0; mg < 2; mg++) {
            rsum[mg] += __shfl_xor(rsum[mg], 16, 64);
            rsum[mg] += __shfl_xor(rsum[mg], 32, 64);
        }

        // epilogue: oacc rows are queries lq*4+r; fetch that query's l from lane lq*4+r
        for (int mg = 0; mg < 2; mg++)
            for (int r = 0; r < 4; r++) {
                float l = __shfl(rsum[mg], lq * 4 + r, 64);
                float inv = 1.0f / l;
                int srow = q0 + wave * 32 + mg * 16 + lq * 4 + r;
                size_t rowbase = ((size_t)(bb * SEQ + srow)) * DM + hh * DK;
                for (int nt = 0; nt < 4; nt++)
                    Cb[rowbase + nt * 16 + lm] = f2b(oacc[mg][nt][r] * inv);
            }
    }
}

// ---------------------------------------------------------------------------
extern "C" void kernel_launch(void* const* d_in, const int* in_sizes, int n_in,
                              void* d_out, int out_size, void* d_ws, size_t ws_size,
                              hipStream_t stream)
{
    const float* x  = (const float*)d_in[0];
    const float* Wq = (const float*)d_in[1];
    const float* Wk = (const float*)d_in[2];
    const float* Wv = (const float*)d_in[3];
    const float* Wo = (const float*)d_in[4];
    float* out = (float*)d_out;

    const size_t TSZ = (size_t)BH * SEQ * DK;   // 8,388,608 elems (16 MB bf16)
    short* Qb  = (short*)d_ws;
    short* Kb  = Qb + TSZ;
    short* Vb  = Kb + TSZ;
    short* XCb = Vb + TSZ;            // x-bf16 during proj; ctx after attention
    short* Wb  = XCb + TSZ;           // 4x [1024][1024] bf16 (Wq,Wk,Wv,Wo)

    // fp32 -> bf16 pre-convert (x + all four W)
    cvt_kernel<<<dim3(4096, 5), 256, 0, stream>>>(x, Wq, Wk, Wv, Wo, XCb, Wb);
    // QKV projection (z: 0=Q,1=K,2=V; V written transposed)
    gemm_nt<false><<<dim3(8, 64, 3), 256, 0, stream>>>(
        XCb, Wb, Qb, Kb, Vb, nullptr);
    // RoPE on Q (with 1/8 scale) and K
    rope_kernel<<<dim3(4096, 2), 256, 0, stream>>>(Qb, Kb);
    // causal flash attention v6 (balanced q-tile pairs) -> ctx (aliases XCb)
    attn_kernel<<<dim3(SEQ / 256, BH), 256, 0, stream>>>(Qb, Kb, Vb, XCb);
    // output projection (fp32 out)
    gemm_nt<true><<<dim3(8, 64, 1), 256, 0, stream>>>(
        XCb, Wb + 3 * (size_t)(DM * DM), nullptr, nullptr, nullptr, out);
}

// Round 3
// 254.077 us; speedup vs baseline: 1.2358x; 1.0956x over previous
//
#include <hip/hip_runtime.h>
#include <hip/hip_bf16.h>

#define BATCH 4
#define SEQ   2048
#define DM    1024
#define NH    16
#define DK    64
#define BH    (BATCH*NH)   // 64

typedef __attribute__((ext_vector_type(8))) short  bv8;   // 8 bf16 (4 VGPRs) MFMA frag
typedef __attribute__((ext_vector_type(4))) short  sv4;   // 4 bf16 (8B)
typedef __attribute__((ext_vector_type(4))) float  f32x4;

__device__ __forceinline__ short f2b(float f) {
    unsigned u = __builtin_bit_cast(unsigned, f);
    u += 0x7fffu + ((u >> 16) & 1u);          // RNE
    return (short)(u >> 16);
}
__device__ __forceinline__ unsigned pk2(float lo, float hi) {  // bf16x2 pack
    unsigned ul = __builtin_bit_cast(unsigned, lo);
    unsigned uh = __builtin_bit_cast(unsigned, hi);
    ul += 0x7fffu + ((ul >> 16) & 1u);
    uh += 0x7fffu + ((uh >> 16) & 1u);
    return (ul >> 16) | (uh & 0xffff0000u);
}
__device__ __forceinline__ float b2f(short s) {
    unsigned u = ((unsigned)(unsigned short)s) << 16;
    return __builtin_bit_cast(float, u);
}

// async global->LDS, 16B per lane; LDS dest = wave-uniform base + lane*16;
// global source is PER-LANE — lanes must cover whole cache lines.
__device__ __forceinline__ void load_lds16(const short* g, short* l) {
    __builtin_amdgcn_global_load_lds(
        (const __attribute__((address_space(1))) void*)g,
        (__attribute__((address_space(3))) void*)l, 16, 0, 0);
}

// ---------------------------------------------------------------------------
// fp32 -> bf16 pre-convert. z=0: x (4096 blocks); z=1..4: Wq,Wk,Wv,Wo (512).
// ---------------------------------------------------------------------------
__global__ __launch_bounds__(256) void cvt_kernel(
    const float* __restrict__ x,
    const float* __restrict__ wq, const float* __restrict__ wk,
    const float* __restrict__ wv, const float* __restrict__ wo,
    short* __restrict__ Xb, short* __restrict__ Wb)
{
    const int z = blockIdx.y;
    const float* src; short* dst; int nblk;
    if (z == 0) { src = x; dst = Xb; nblk = 4096; }
    else {
        src = (z == 1) ? wq : (z == 2) ? wk : (z == 3) ? wv : wo;
        dst = Wb + (size_t)(z - 1) * (DM * DM);
        nblk = 512;
    }
    if ((int)blockIdx.x >= nblk) return;
    int idx = blockIdx.x * 256 + threadIdx.x;      // 8-elem chunk
    const float4* s4 = (const float4*)src + (size_t)idx * 2;
    float4 a = s4[0], b = s4[1];
    bv8 o;
    o[0] = f2b(a.x); o[1] = f2b(a.y); o[2] = f2b(a.z); o[3] = f2b(a.w);
    o[4] = f2b(b.x); o[5] = f2b(b.y); o[6] = f2b(b.z); o[7] = f2b(b.w);
    *(bv8*)(dst + (size_t)idx * 8) = o;
}

// ---------------------------------------------------------------------------
// GEMM (NT, all-bf16). v7 changes:
//  (a) XCD-chunked block remap: dispatch id -> logical id so blocks sharing
//      an A-tile (same bm, all bn) co-reside on one XCD's L2. Round-robin
//      placement means xcd = flat&7; chunk = nwg/8 is exact (nwg % 8 == 0),
//      so the remap is bijective.
//  (b) bz==2 (V): compute V^T = Wv * X^T directly via operand swap. Output
//      rows become the d-dimension and cols the X-rows, so the [BH][DK][SEQ]
//      store is s-contiguous (32B segments) instead of a 2B scatter at 4KB
//      stride. Same k-summation order -> bit-identical V values.
// ---------------------------------------------------------------------------
template<bool FINAL>
__global__ __launch_bounds__(256) void gemm_nt(
    const short* __restrict__ A, const short* __restrict__ Wall,
    short* __restrict__ Oq, short* __restrict__ Ok, short* __restrict__ Ov,
    float* __restrict__ FO)
{
    constexpr int K = 1024;
    __shared__ __align__(16) short As[128 * 64];   // 16 KB, slot16(r,c8)=r*8+(c8^(r&7))
    __shared__ __align__(16) short Ws[128 * 64];

    // (a) XCD-chunked remap
    const int flat  = (int)blockIdx.x + 8 * (int)blockIdx.y + 512 * (int)blockIdx.z;
    const int chunk = (512 * (int)gridDim.z) >> 3;
    const int L  = (flat & 7) * chunk + (flat >> 3);
    const int bn = L & 7, bm = (L >> 3) & 63, bz = L >> 9;

    // (b) operand roles
    const short* Ap; const short* Wp; int row0, col0;
    if (!FINAL && bz == 2) {
        Ap = Wall + 2 * (size_t)(DM * DM);   // Wv rows -> output rows (h*64+d)
        Wp = A;                              // X rows  -> output cols (b*2048+s)
        row0 = bn * 128; col0 = bm * 128;
    } else {
        Ap = A;
        Wp = Wall + (size_t)bz * (DM * DM);
        row0 = bm * 128; col0 = bn * 128;
    }

    const int tid = threadIdx.x;
    const int wave = tid >> 6, lane = tid & 63, lm = lane & 15, lq = lane >> 4;
    const int wr = wave >> 1, wc = wave & 1;

    f32x4 acc[4][4];
    for (int i = 0; i < 4; i++)
        for (int j = 0; j < 4; j++)
            acc[i][j] = f32x4{0.f, 0.f, 0.f, 0.f};

    const int rI = lane >> 3;              // row within instruction (0..7)
    const int cS = (lane & 7) ^ rI;        // swizzled 16B chunk (0..7)
    const short* gA[4]; const short* gW[4];
    short* lA[4]; short* lW[4];
    for (int j = 0; j < 4; j++) {
        int rl = wave * 32 + j * 8;
        gA[j] = Ap + (size_t)(row0 + rl + rI) * K + cS * 8;
        gW[j] = Wp + (size_t)(col0 + rl + rI) * K + cS * 8;
        lA[j] = &As[rl * 64];
        lW[j] = &Ws[rl * 64];
    }

    for (int kk = 0; kk < K; kk += 64) {
        for (int j = 0; j < 4; j++) {
            load_lds16(gA[j], lA[j]);  gA[j] += 64;
            load_lds16(gW[j], lW[j]);  gW[j] += 64;
        }
        __syncthreads();

        for (int h = 0; h < 2; h++) {
            bv8 af[4], bf[4];
            for (int mt = 0; mt < 4; mt++) {
                int r = wr * 64 + mt * 16 + lm;
                af[mt] = *(const bv8*)&As[r * 64 + (((h * 4 + lq) ^ (lm & 7)) * 8)];
            }
            for (int nt = 0; nt < 4; nt++) {
                int r = wc * 64 + nt * 16 + lm;
                bf[nt] = *(const bv8*)&Ws[r * 64 + (((h * 4 + lq) ^ (lm & 7)) * 8)];
            }
            for (int mt = 0; mt < 4; mt++)
                for (int nt = 0; nt < 4; nt++)
                    acc[mt][nt] = __builtin_amdgcn_mfma_f32_16x16x32_bf16(af[mt], bf[nt], acc[mt][nt], 0, 0, 0);
        }
        __syncthreads();
    }

    for (int mt = 0; mt < 4; mt++) {
        int mbase = row0 + wr * 64 + mt * 16 + lq * 4;
        for (int nt = 0; nt < 4; nt++) {
            int n = col0 + wc * 64 + nt * 16 + lm;
            for (int r = 0; r < 4; r++) {
                float v = acc[mt][nt][r];
                int row = mbase + r;
                if constexpr (FINAL) {
                    FO[(size_t)row * DM + n] = v;
                } else if (bz == 2) {
                    // row = Wv-row = h*64+d ; n = X-row = b*2048+s (s-contig store)
                    int h = row >> 6, d = row & 63;
                    int b = n >> 11, s = n & 2047;
                    Ov[((size_t)((b * NH + h) * DK + d)) * SEQ + s] = f2b(v);
                } else {
                    int b = row >> 11, s = row & 2047;
                    int h = n >> 6, d = n & 63;
                    short* dst = (bz == 0) ? Oq : Ok;
                    dst[((size_t)((b * NH + h) * SEQ + s)) * DK + d] = f2b(v);
                }
            }
        }
    }
}

// ---------------------------------------------------------------------------
// RoPE in-place on [BH][S][64] bf16. grid.y: 0=Q (also applies 1/8 scale), 1=K.
// ---------------------------------------------------------------------------
__global__ __launch_bounds__(256) void rope_kernel(short* __restrict__ Qb, short* __restrict__ Kb)
{
    short* T = blockIdx.y ? Kb : Qb;
    const float scale = blockIdx.y ? 1.0f : 0.125f;
    int idx = blockIdx.x * 256 + threadIdx.x;     // 8-elem chunk
    int s  = (idx >> 3) & (SEQ - 1);
    int d0 = (idx & 7) * 8;
    bv8 v = *(const bv8*)(T + (size_t)idx * 8);
    bv8 o;
    for (int j = 0; j < 4; j++) {
        int i = (d0 >> 1) + j;                    // pair index 0..31
        float invrev = __builtin_amdgcn_exp2f((float)i * -0.41522499f) * 0.15915494309f;
        float rev = __builtin_amdgcn_fractf((float)s * invrev);
        float sn = __builtin_amdgcn_sinf(rev);
        float cs = __builtin_amdgcn_cosf(rev);
        float e  = b2f(v[2 * j]);
        float od = b2f(v[2 * j + 1]);
        o[2 * j]     = f2b((e * cs - od * sn) * scale);
        o[2 * j + 1] = f2b((e * sn + od * cs) * scale);
    }
    *(bv8*)(T + (size_t)idx * 8) = o;
}

// ---------------------------------------------------------------------------
// Flash attention v6 (balanced q-tile pairs). grid (S/256, BH), 256 thr =
// 4 waves; wave owns 32 q-rows. Every block processes the complementary pair
// (15-x, x): exactly 34 tile-steps per block, balanced by construction.
// K/V staged via async global_load_lds (double-buffered, XOR-swizzled);
// S^T = mfma(kf, qf) so each lane owns one query (lm) and 16 keys; mask/exp/
// l-sum are lane-local; PV uses the psi key-order lane-local repack (8 pk2s)
// + two contiguous 8B LDS reads per (nt,h) from the swizzled V^T tile.
// LDS = 32 KB.
// ---------------------------------------------------------------------------
__global__ __launch_bounds__(256, 4) void attn_kernel(
    const short* __restrict__ Qb, const short* __restrict__ Kb,
    const short* __restrict__ Vb, short* __restrict__ Cb)
{
    __shared__ __align__(16) short Ks[2][4096];   // [buf][key*64 + swz] 8KB/buf
    __shared__ __align__(16) short Vs[2][4096];   // [buf][d*64 + swz]

    const int bh = blockIdx.y;
    const int tid = threadIdx.x, wave = tid >> 6, lane = tid & 63;
    const int lm = lane & 15, lq = lane >> 4;
    const size_t base = (size_t)bh * SEQ * DK;

    const int sr = lane >> 3;
    const int sc = (lane & 7) ^ sr;
    const short* gK0 = Kb + base + (size_t)(wave * 16 + sr) * DK + sc * 8;
    const short* gK1 = Kb + base + (size_t)(wave * 16 + 8 + sr) * DK + sc * 8;
    const short* gV0 = Vb + base + (size_t)(wave * 16 + sr) * SEQ + sc * 8;
    const short* gV1 = Vb + base + (size_t)(wave * 16 + 8 + sr) * SEQ + sc * 8;
    short* lK0[2] = { &Ks[0][(wave * 16) * 64],     &Ks[1][(wave * 16) * 64] };
    short* lK1[2] = { &Ks[0][(wave * 16 + 8) * 64], &Ks[1][(wave * 16 + 8) * 64] };
    short* lV0[2] = { &Vs[0][(wave * 16) * 64],     &Vs[1][(wave * 16) * 64] };
    short* lV1[2] = { &Vs[0][(wave * 16 + 8) * 64], &Vs[1][(wave * 16 + 8) * 64] };

    const int sw = lm & 7;
    const int bb = bh >> 4, hh = bh & 15;
    constexpr int NQT = SEQ / 128;                 // 16 q-tiles

    for (int pass = 0; pass < 2; ++pass) {
        // complementary pair: pass 0 -> heavy qt = 15-x, pass 1 -> light qt = x
        const int qt = pass ? (int)blockIdx.x : (NQT - 1 - (int)blockIdx.x);
        const int q0 = qt * 128;

        // Q frags (used as MFMA B-operand; same lane layout as A)
        bv8 aQ[2][2];
        for (int mg = 0; mg < 2; mg++) {
            const short* qp = Qb + base + (size_t)(q0 + wave * 32 + mg * 16 + lm) * DK + lq * 8;
            aQ[mg][0] = *(const bv8*)qp;
            aQ[mg][1] = *(const bv8*)(qp + 32);
        }

        f32x4 oacc[2][4];
        float rsum[2] = {0.f, 0.f};               // per-lane: one query (lm) per mg
        for (int mg = 0; mg < 2; mg++)
            for (int nt = 0; nt < 4; nt++) oacc[mg][nt] = f32x4{0.f, 0.f, 0.f, 0.f};

        const int last = 2 * qt + 1;
        const int qrow_base = q0 + wave * 32 + lm;    // + mg*16 -> this lane's query

        load_lds16(gK0, lK0[0]);  load_lds16(gK1, lK1[0]);
        load_lds16(gV0, lV0[0]);  load_lds16(gV1, lV1[0]);
        __syncthreads();

        for (int kt = 0; kt <= last; ++kt) {
            const int b = kt & 1;
            if (kt < last) {                           // prefetch overlaps compute
                const size_t ko = (size_t)(kt + 1) * 64 * DK;
                const size_t vo = (size_t)(kt + 1) * 64;
                load_lds16(gK0 + ko, lK0[b ^ 1]);  load_lds16(gK1 + ko, lK1[b ^ 1]);
                load_lds16(gV0 + vo, lV0[b ^ 1]);  load_lds16(gV1 + vo, lV1[b ^ 1]);
            }

            // S^T tiles: t[mg][nt] reg r = S[query mg*16+lm][key kt*64+nt*16+lq*4+r]
            f32x4 t[2][4];
            for (int nt = 0; nt < 4; nt++) {
                const short* kp = &Ks[b][(nt * 16 + lm) * 64];
                bv8 kf0 = *(const bv8*)(kp + ((lq ^ sw) * 8));
                bv8 kf1 = *(const bv8*)(kp + (((4 + lq) ^ sw) * 8));
                for (int mg = 0; mg < 2; mg++) {
                    f32x4 z = f32x4{0.f, 0.f, 0.f, 0.f};
                    z = __builtin_amdgcn_mfma_f32_16x16x32_bf16(kf0, aQ[mg][0], z, 0, 0, 0);
                    z = __builtin_amdgcn_mfma_f32_16x16x32_bf16(kf1, aQ[mg][1], z, 0, 0, 0);
                    t[mg][nt] = z;
                }
            }

            // mask (diagonal region only) + exp + lane-local l-sum + lane-local
            // repack into PV A-frags (key order psi: j<4 -> tile 2h, j>=4 -> 2h+1)
            bv8 aP[2][2];
            for (int mg = 0; mg < 2; mg++) {
                const int qrow = qrow_base + mg * 16;
                if (kt >= 2 * qt) {
                    for (int nt = 0; nt < 4; nt++) {
                        int keyb = kt * 64 + nt * 16 + lq * 4;
                        for (int r = 0; r < 4; r++)
                            t[mg][nt][r] = (keyb + r <= qrow) ? t[mg][nt][r] : -1e30f;
                    }
                }
                for (int nt = 0; nt < 4; nt++)
                    for (int r = 0; r < 4; r++) {
                        float p = __builtin_amdgcn_exp2f(t[mg][nt][r] * 1.44269504f);
                        rsum[mg] += p;
                        t[mg][nt][r] = p;
                    }
                for (int h = 0; h < 2; h++) {
                    union { unsigned u[4]; bv8 v; } pk;
                    pk.u[0] = pk2(t[mg][2 * h][0],     t[mg][2 * h][1]);
                    pk.u[1] = pk2(t[mg][2 * h][2],     t[mg][2 * h][3]);
                    pk.u[2] = pk2(t[mg][2 * h + 1][0], t[mg][2 * h + 1][1]);
                    pk.u[3] = pk2(t[mg][2 * h + 1][2], t[mg][2 * h + 1][3]);
                    aP[mg][h] = pk.v;
                }
            }

            // O += P V with the psi key order: B-frag element j on lane (lq,lm) =
            // V[32h + (j>>2)*16 + lq*4 + (j&3)][d = nt*16+lm] -> two 8B reads.
            for (int nt = 0; nt < 4; nt++) {
                const short* vrow = &Vs[b][(nt * 16 + lm) * 64];
                for (int h = 0; h < 2; h++) {
                    int c8 = h * 4 + (lq >> 1);
                    union { sv4 q[2]; bv8 v; } vv;
                    vv.q[0] = *(const sv4*)(vrow + ((c8 ^ sw) * 8)       + (lq & 1) * 4);
                    vv.q[1] = *(const sv4*)(vrow + (((c8 ^ 2) ^ sw) * 8) + (lq & 1) * 4);
                    for (int mg = 0; mg < 2; mg++)
                        oacc[mg][nt] = __builtin_amdgcn_mfma_f32_16x16x32_bf16(aP[mg][h], vv.v, oacc[mg][nt], 0, 0, 0);
                }
            }
            __syncthreads();   // releases buf b for the next prefetch
        }

        // l-sum: add the 4 lq quadrants (each lane then has full sum for query lm)
        for (int mg = 0; mg < 2; mg++) {
            rsum[mg] += __shfl_xor(rsum[mg], 16, 64);
            rsum[mg] += __shfl_xor(rsum[mg], 32, 64);
        }

        // epilogue: oacc rows are queries lq*4+r; fetch that query's l from lane lq*4+r
        for (int mg = 0; mg < 2; mg++)
            for (int r = 0; r < 4; r++) {
                float l = __shfl(rsum[mg], lq * 4 + r, 64);
                float inv = 1.0f / l;
                int srow = q0 + wave * 32 + mg * 16 + lq * 4 + r;
                size_t rowbase = ((size_t)(bb * SEQ + srow)) * DM + hh * DK;
                for (int nt = 0; nt < 4; nt++)
                    Cb[rowbase + nt * 16 + lm] = f2b(oacc[mg][nt][r] * inv);
            }
    }
}

// ---------------------------------------------------------------------------
extern "C" void kernel_launch(void* const* d_in, const int* in_sizes, int n_in,
                              void* d_out, int out_size, void* d_ws, size_t ws_size,
                              hipStream_t stream)
{
    const float* x  = (const float*)d_in[0];
    const float* Wq = (const float*)d_in[1];
    const float* Wk = (const float*)d_in[2];
    const float* Wv = (const float*)d_in[3];
    const float* Wo = (const float*)d_in[4];
    float* out = (float*)d_out;

    const size_t TSZ = (size_t)BH * SEQ * DK;   // 8,388,608 elems (16 MB bf16)
    short* Qb  = (short*)d_ws;
    short* Kb  = Qb + TSZ;
    short* Vb  = Kb + TSZ;
    short* XCb = Vb + TSZ;            // x-bf16 during proj; ctx after attention
    short* Wb  = XCb + TSZ;           // 4x [1024][1024] bf16 (Wq,Wk,Wv,Wo)

    // fp32 -> bf16 pre-convert (x + all four W)
    cvt_kernel<<<dim3(4096, 5), 256, 0, stream>>>(x, Wq, Wk, Wv, Wo, XCb, Wb);
    // QKV projection (z: 0=Q,1=K,2=V; V computed transposed via operand swap)
    gemm_nt<false><<<dim3(8, 64, 3), 256, 0, stream>>>(
        XCb, Wb, Qb, Kb, Vb, nullptr);
    // RoPE on Q (with 1/8 scale) and K
    rope_kernel<<<dim3(4096, 2), 256, 0, stream>>>(Qb, Kb);
    // causal flash attention v6 (balanced q-tile pairs) -> ctx (aliases XCb)
    attn_kernel<<<dim3(SEQ / 256, BH), 256, 0, stream>>>(Qb, Kb, Vb, XCb);
    // output projection (fp32 out)
    gemm_nt<true><<<dim3(8, 64, 1), 256, 0, stream>>>(
        XCb, Wb + 3 * (size_t)(DM * DM), nullptr, nullptr, nullptr, out);
}